// Round 1
// baseline (242.171 us; speedup 1.0000x reference)
//
#include <hip/hip_runtime.h>

#define NN    10000
#define EE    160000
#define CINC  32
#define COUTC 32
#define RM    18            // R*M
#define KK    576           // RM*CINC
#define CAP   64            // bucket capacity (mean degree 16)
#define NPB   4             // nodes per block (1 wave each), 256 threads
#define TILE_SH 1152        // shorts per stenT tile: 4 comp * 18 rm * 16 edges
#define POS_SH  4608        // shorts per node position (fixed 4-tile stride)
#define LTILE   1168        // LDS tile stride in shorts (+16 pad for banks)
#define AROW  592           // agg row stride in bf16 elems (576 + 16 pad)
#define EPSV  1e-8f

typedef __attribute__((ext_vector_type(8)))  short bf16x8;
typedef __attribute__((ext_vector_type(4)))  float f32x4;
typedef __attribute__((ext_vector_type(16))) float f32x16;

__device__ inline short f2bf(float f) {            // round-to-nearest-even
    unsigned u = __float_as_uint(f);
    u = (u + 0x7FFF + ((u >> 16) & 1)) >> 16;
    return (short)u;
}
__device__ inline float bf2f(unsigned short h) {
    return __uint_as_float(((unsigned)h) << 16);
}
// split fp32 -> (hi, lo) bf16 pair, packed: x = rehi|relo<<16, y = imhi|imlo<<16
__device__ inline uint2 packsplit(float re, float im) {
    unsigned short rh = (unsigned short)f2bf(re);
    unsigned short rl = (unsigned short)f2bf(re - bf2f(rh));
    unsigned short ih = (unsigned short)f2bf(im);
    unsigned short il = (unsigned short)f2bf(im - bf2f(ih));
    return make_uint2((unsigned)rh | ((unsigned)rl << 16),
                      (unsigned)ih | ((unsigned)il << 16));
}

// ---------------- build: weight planes + bucket scatter + x split-bf16 ----------------
__global__ void __launch_bounds__(256)
k_build(const int* __restrict__ edges, int* __restrict__ cursor,
        const float* __restrict__ w1, const float* __restrict__ off1,
        const float* __restrict__ w2, const float* __restrict__ off2,
        short* __restrict__ Wcb1, short* __restrict__ Wcb2,
        int2* __restrict__ sei,
        const float2* __restrict__ xc, uint2* __restrict__ xbf)
{
    int i = blockIdx.x*blockDim.x + threadIdx.x;
    if (i < KK*COUTC) {
        int d = i & 31;
        int k = i >> 5;                 // rm*32 + c
        int c = k & 31;
        float o1 = off1[c*COUTC + d];
        float o2 = off2[c*COUTC + d];
        float s1 = sinf(o1), c1 = cosf(o1);
        float s2 = sinf(o2), c2 = cosf(o2);
        Wcb1[d*KK + k]            = f2bf(w1[i]*c1);
        Wcb1[KK*COUTC + d*KK + k] = f2bf(w1[i]*s1);
        Wcb2[d*KK + k]            = f2bf(w2[i]*c2);
        Wcb2[KK*COUTC + d*KK + k] = f2bf(w2[i]*s2);
    }
    if (i < EE) {
        int src = edges[2*i];
        int tgt = edges[2*i+1];
        int pos = atomicAdd(&cursor[tgt], 1);
        if (pos < CAP) sei[tgt*CAP + pos] = make_int2(src, i);
    }
    if (i < NN*CINC) {
        float2 v = xc[i];
        xbf[i] = packsplit(v.x, v.y);
    }
}

// ---------------- degree ordering (desc), parallelized 3-kernel counting sort ----------------
__global__ void __launch_bounds__(256)
k_hist(const int* __restrict__ cursor, int* __restrict__ bins) {
    int n = blockIdx.x*blockDim.x + threadIdx.x;
    if (n < NN) { int d = cursor[n]; if (d > CAP) d = CAP; atomicAdd(&bins[d], 1); }
}
__global__ void k_prefix(const int* __restrict__ bins, int* __restrict__ base) {
    if (threadIdx.x == 0) {
        int run = 0;
        for (int b = CAP; b >= 0; --b) { base[b] = run; run += bins[b]; }
    }
}
__global__ void __launch_bounds__(256)
k_scatter(const int* __restrict__ cursor, int* __restrict__ base, int* __restrict__ order) {
    int n = blockIdx.x*blockDim.x + threadIdx.x;
    if (n < NN) {
        int d = cursor[n]; if (d > CAP) d = CAP;
        int r = atomicAdd(&base[d], 1);
        order[r] = n;
    }
}

// ---------------- transpose: per-node MFMA-ready split-bf16 stencil tiles ----------------
// One wave per sorted position p. Lane l owns bucket slot l. Output layout per
// K-tile (16 edges): [comp(rehi,relo,imhi,imlo)][rm(18)][edge(16)] bf16, so a
// conv lane (rm=l&31, oct=l>>5) reads its 8-edge A-fragment as one 16B load.
// Tail slots (>= cnt) are zero -> garbage B contributions are annihilated.
__global__ void __launch_bounds__(256)
k_transpose(const int* __restrict__ cursor, const int* __restrict__ order,
            const int2* __restrict__ sei, const float4* __restrict__ stenc4,
            short* __restrict__ stenT, int* __restrict__ srcs_s, int* __restrict__ nt_s)
{
    __shared__ __align__(16) short S[NPB*4*LTILE];   // 4 waves * 4 tiles * 2336 B
    int t = threadIdx.x, g = t >> 6, l = t & 63;
    int p = blockIdx.x*NPB + g;
    int n = order[p];
    int cnt = cursor[n]; if (cnt > CAP) cnt = CAP;
    int nt = (cnt + 15) >> 4;
    if (l == 0) nt_s[p] = nt;

    int2 se = make_int2(0, 0);
    if (l < cnt) se = sei[n*CAP + l];
    srcs_s[p*CAP + l] = se.x;                        // 0 for invalid slots

    float4 st[9];
    #pragma unroll
    for (int j = 0; j < 9; ++j) st[j] = make_float4(0.f,0.f,0.f,0.f);
    if (l < cnt) {
        const float4* sp = stenc4 + (size_t)se.y*9;
        #pragma unroll
        for (int j = 0; j < 9; ++j) st[j] = sp[j];
    }

    short* basep = S + g*(4*LTILE) + (l>>4)*LTILE + (l&15);
    #pragma unroll
    for (int j = 0; j < 9; ++j) {
        float4 s = st[j];
        {
            int rm = 2*j;
            short rh = f2bf(s.x); short rl = f2bf(s.x - bf2f((unsigned short)rh));
            short ih = f2bf(s.y); short il = f2bf(s.y - bf2f((unsigned short)ih));
            short* bp = basep + rm*16;
            bp[0] = rh; bp[288] = rl; bp[576] = ih; bp[864] = il;
        }
        {
            int rm = 2*j + 1;
            short rh = f2bf(s.z); short rl = f2bf(s.z - bf2f((unsigned short)rh));
            short ih = f2bf(s.w); short il = f2bf(s.w - bf2f((unsigned short)ih));
            short* bp = basep + rm*16;
            bp[0] = rh; bp[288] = rl; bp[576] = ih; bp[864] = il;
        }
    }
    __syncthreads();                                  // (wave-local really; cheap)

    size_t gbase = (size_t)p * POS_SH;
    for (int tt = 0; tt < nt; ++tt) {
        const short* src = S + g*(4*LTILE) + tt*LTILE;
        short* dst = stenT + gbase + tt*TILE_SH;
        #pragma unroll
        for (int it = 0; it < 3; ++it) {
            int idx = it*64 + l;
            if (idx < 144)                            // 144 * 16B = 2304 B
                *(int4*)(dst + idx*8) = *(const int4*)(src + idx*8);
        }
    }
}

// ---------------- fused conv: MFMA aggregation (split-bf16) + MFMA einsum ----------------
// 4 waves/block, 1 node/wave. Per K-step (16 edges):
//   A (stencil): 4 contiguous 16B loads from stenT (lane rm=l&31<18, oct=l>>5)
//   B (x): 8 coalesced 8B gathers of packed split-bf16 x, repacked to planes
//   12x mfma_f32_32x32x16_bf16: 3-term hi/lo split x complex (re,im)
// agg rows 18..31 are exact zeros (A zero rows); einsum only reads k<576.
template<bool FINAL>
__global__ void __launch_bounds__(256)
k_conv(const uint2* __restrict__ xbf,     // packed split-bf16 input, (NN,32)
       const int*  __restrict__ order,
       const int*  __restrict__ nt_s,     // (NN) K-tiles per position
       const int*  __restrict__ srcs_s,   // (NN*CAP) src per slot, sorted pos
       const short* __restrict__ stenT,   // (NN*POS_SH) transposed stencil
       const short* __restrict__ Wcb,     // [re|im][32][576] bf16
       const float* __restrict__ bias,    // (32)
       const float2* __restrict__ xres,   // (NN,32) original xc (FINAL)
       const float2* __restrict__ resw,   // (32,32) complex (FINAL)
       float2* __restrict__ out,          // (NN,32) complex (FINAL)
       uint2* __restrict__ outbf)         // packed split-bf16 h (!FINAL)
{
    __shared__ __align__(16) short aggS[2*NPB*AROW];  // 9472 B, later dump
    __shared__ int nid[NPB];
    int t = threadIdx.x, g = t >> 6, l = t & 63;
    int p = blockIdx.x*NPB + g;
    if (t < NPB) nid[t] = order[blockIdx.x*NPB + t];

    int c = l & 31, oct = l >> 5;
    int nt = nt_s[p];
    const short* At = stenT + (size_t)p * POS_SH;
    const int* sr = srcs_s + p*CAP;
    bool arow = (c < RM);

    f32x16 Pre = (f32x16)(0.f), Pim = (f32x16)(0.f);
    bf16x8 z8 = {0,0,0,0,0,0,0,0};

    for (int tt = 0; tt < nt; ++tt) {
        bf16x8 A0, A1, A2, A3;                        // rehi, relo, imhi, imlo
        const short* Ab = At + tt*TILE_SH + c*16 + oct*8;
        if (arow) {
            A0 = *(const bf16x8*)(Ab);
            A1 = *(const bf16x8*)(Ab + 288);
            A2 = *(const bf16x8*)(Ab + 576);
            A3 = *(const bf16x8*)(Ab + 864);
        } else { A0 = z8; A1 = z8; A2 = z8; A3 = z8; }

        int4 sa = *(const int4*)(sr + tt*16 + oct*8);
        int4 sb = *(const int4*)(sr + tt*16 + oct*8 + 4);
        int sl[8] = {sa.x, sa.y, sa.z, sa.w, sb.x, sb.y, sb.z, sb.w};
        uint2 xv[8];
        #pragma unroll
        for (int j = 0; j < 8; ++j) xv[j] = xbf[(sl[j] << 5) | c];

        union U { unsigned u[4]; bf16x8 v; };
        U Brh, Brl, Bih, Bil, Bnh, Bnl;
        #pragma unroll
        for (int k2 = 0; k2 < 4; ++k2) {
            unsigned x0 = xv[2*k2].x, x1 = xv[2*k2+1].x;
            unsigned y0 = xv[2*k2].y, y1 = xv[2*k2+1].y;
            Brh.u[k2] = (x0 & 0xffffu) | (x1 << 16);
            Brl.u[k2] = (x0 >> 16)     | (x1 & 0xffff0000u);
            Bih.u[k2] = (y0 & 0xffffu) | (y1 << 16);
            Bil.u[k2] = (y0 >> 16)     | (y1 & 0xffff0000u);
            Bnh.u[k2] = Bih.u[k2] ^ 0x80008000u;
            Bnl.u[k2] = Bil.u[k2] ^ 0x80008000u;
        }
        // P_re = re*re - im*im   (3-term split each)
        Pre = __builtin_amdgcn_mfma_f32_32x32x16_bf16(A0, Brh.v, Pre, 0, 0, 0);
        Pre = __builtin_amdgcn_mfma_f32_32x32x16_bf16(A0, Brl.v, Pre, 0, 0, 0);
        Pre = __builtin_amdgcn_mfma_f32_32x32x16_bf16(A1, Brh.v, Pre, 0, 0, 0);
        Pre = __builtin_amdgcn_mfma_f32_32x32x16_bf16(A2, Bnh.v, Pre, 0, 0, 0);
        Pre = __builtin_amdgcn_mfma_f32_32x32x16_bf16(A2, Bnl.v, Pre, 0, 0, 0);
        Pre = __builtin_amdgcn_mfma_f32_32x32x16_bf16(A3, Bnh.v, Pre, 0, 0, 0);
        // P_im = re*im + im*re
        Pim = __builtin_amdgcn_mfma_f32_32x32x16_bf16(A0, Bih.v, Pim, 0, 0, 0);
        Pim = __builtin_amdgcn_mfma_f32_32x32x16_bf16(A0, Bil.v, Pim, 0, 0, 0);
        Pim = __builtin_amdgcn_mfma_f32_32x32x16_bf16(A1, Bih.v, Pim, 0, 0, 0);
        Pim = __builtin_amdgcn_mfma_f32_32x32x16_bf16(A2, Brh.v, Pim, 0, 0, 0);
        Pim = __builtin_amdgcn_mfma_f32_32x32x16_bf16(A2, Brl.v, Pim, 0, 0, 0);
        Pim = __builtin_amdgcn_mfma_f32_32x32x16_bf16(A3, Brh.v, Pim, 0, 0, 0);
    }

    // write agg rows (C/D layout: col=lane&31, row=(reg&3)+8*(reg>>2)+4*oct)
    {
        short* aR = aggS + g*AROW;
        short* aI = aggS + NPB*AROW + g*AROW;
        #pragma unroll
        for (int reg = 0; reg < 16; ++reg) {
            int rm = (reg & 3) + 8*(reg >> 2) + 4*oct;
            if (rm < RM) {
                aR[rm*32 + c] = f2bf(Pre[reg]);
                aI[rm*32 + c] = f2bf(Pim[reg]);
            }
        }
    }
    __syncthreads();

    // ---- einsum via MFMA 16x16x32: D[m][d] = sum_k agg[m][k] * Wc[k][d] ----
    int quad = l >> 4;
    int nn16 = l & 15;
    int mrow = (nn16 < NPB) ? nn16 : NPB-1;           // rows >= 4 dup of 3, ignored
    int rm0 = (g < 2) ? 5*g : 10 + 4*(g-2);           // waves: 5,5,4,4 rm rows
    int nrm = (g < 2) ? 5 : 4;
    const short* aggR = aggS;
    const short* aggI = aggS + NPB*AROW;
    const short* Wr = Wcb;
    const short* Wi = Wcb + KK*COUTC;

    f32x4 Prr[2], Pii[2], Pri[2], Pir[2];
    #pragma unroll
    for (int n2 = 0; n2 < 2; ++n2) {
        Prr[n2] = (f32x4)(0.f); Pii[n2] = (f32x4)(0.f);
        Pri[n2] = (f32x4)(0.f); Pir[n2] = (f32x4)(0.f);
    }
    for (int r = rm0; r < rm0 + nrm; ++r) {
        int koff = r*32 + quad*8;
        bf16x8 ar = *(const bf16x8*)(aggR + mrow*AROW + koff);
        bf16x8 ai = *(const bf16x8*)(aggI + mrow*AROW + koff);
        #pragma unroll
        for (int n2 = 0; n2 < 2; ++n2) {
            int d = n2*16 + nn16;
            bf16x8 br = *(const bf16x8*)(Wr + d*KK + koff);
            bf16x8 bi = *(const bf16x8*)(Wi + d*KK + koff);
            Prr[n2] = __builtin_amdgcn_mfma_f32_16x16x32_bf16(ar, br, Prr[n2], 0, 0, 0);
            Pii[n2] = __builtin_amdgcn_mfma_f32_16x16x32_bf16(ai, bi, Pii[n2], 0, 0, 0);
            Pri[n2] = __builtin_amdgcn_mfma_f32_16x16x32_bf16(ar, bi, Pri[n2], 0, 0, 0);
            Pir[n2] = __builtin_amdgcn_mfma_f32_16x16x32_bf16(ai, br, Pir[n2], 0, 0, 0);
        }
    }
    __syncthreads();                                  // agg reads done; reuse as dump

    float2* dump = (float2*)aggS;                     // [wave][m][d] float2, 4 KB
    if (quad == 0) {                                  // C rows 0..3 = nodes
        #pragma unroll
        for (int reg = 0; reg < 4; ++reg) {
            int m = reg;
            #pragma unroll
            for (int n2 = 0; n2 < 2; ++n2) {
                int d = n2*16 + nn16;
                dump[((size_t)g*NPB + m)*COUTC + d] =
                    make_float2(Prr[n2][reg] - Pii[n2][reg],
                                Pri[n2][reg] + Pir[n2][reg]);
            }
        }
    }
    __syncthreads();

    // ---- reduce 4 waves, residual, nonlinearity ----
    if (t < NPB*COUTC) {
        int m = t >> 5, d = t & 31;
        int n = nid[m];
        float2 hv = make_float2(0.f, 0.f);
        #pragma unroll
        for (int w = 0; w < NPB; ++w) {
            float2 v = dump[((size_t)w*NPB + m)*COUTC + d];
            hv.x += v.x; hv.y += v.y;
        }
        if (FINAL) {
            const float2* xr = xres + (size_t)n * CINC;
            #pragma unroll
            for (int cc = 0; cc < CINC; ++cc) {
                float2 xvv = xr[cc];
                float2 w = resw[cc*COUTC + d];
                hv.x += xvv.x*w.x - xvv.y*w.y;
                hv.y += xvv.x*w.y + xvv.y*w.x;
            }
        }
        float mag = sqrtf(hv.x*hv.x + hv.y*hv.y);
        float num = mag + bias[d]; if (num < 0.f) num = 0.f;
        float den = (mag > EPSV) ? mag : EPSV;
        float f = num / den;
        if (FINAL) out[(size_t)n*COUTC + d] = make_float2(f*hv.x, f*hv.y);
        else       outbf[(size_t)n*COUTC + d] = packsplit(f*hv.x, f*hv.y);
    }
}

// ---------------- launch ----------------
extern "C" void kernel_launch(void* const* d_in, const int* in_sizes, int n_in,
                              void* d_out, int out_size, void* d_ws, size_t ws_size,
                              hipStream_t stream) {
    const float2* xc   = (const float2*)d_in[0];   // (N,32,2) -> complex
    const int*   edges = (const int*)  d_in[1];    // (E,2)
    const float4* stenc4 = (const float4*)d_in[2]; // (E,6,3,2) -> (E,9) float4
    const float* w1    = (const float*)d_in[3];
    const float* off1  = (const float*)d_in[4];
    const float* b1    = (const float*)d_in[5];
    const float* w2    = (const float*)d_in[6];
    const float* off2  = (const float*)d_in[7];
    const float* b2    = (const float*)d_in[8];
    const float2* resw = (const float2*)d_in[9];   // (32,32) complex
    float2* out = (float2*)d_out;

    char* ws = (char*)d_ws;
    size_t o = 0;
    auto alloc = [&](size_t bytes) {
        o = (o + 255) & ~(size_t)255;
        size_t r = o; o += bytes; return r;
    };
    int*    cursor = (int*)  (ws + alloc((NN + 66)*sizeof(int)));  // +bins tail
    int*    bins   = cursor + NN;
    int*    base   = (int*)  (ws + alloc(66*sizeof(int)));
    int*    order  = (int*)  (ws + alloc(NN*sizeof(int)));
    int2*   sei    = (int2*) (ws + alloc((size_t)NN*CAP*sizeof(int2)));
    uint2*  xbf    = (uint2*)(ws + alloc((size_t)NN*CINC*sizeof(uint2)));
    uint2*  hbf    = (uint2*)(ws + alloc((size_t)NN*CINC*sizeof(uint2)));
    int*    srcs_s = (int*)  (ws + alloc((size_t)NN*CAP*sizeof(int)));
    int*    nt_s   = (int*)  (ws + alloc(NN*sizeof(int)));
    short*  Wcb1   = (short*)(ws + alloc((size_t)2*KK*COUTC*sizeof(short)));
    short*  Wcb2   = (short*)(ws + alloc((size_t)2*KK*COUTC*sizeof(short)));
    short*  stenT  = (short*)(ws + alloc((size_t)NN*POS_SH*sizeof(short)));
    (void)ws_size; (void)in_sizes; (void)n_in; (void)out_size;

    hipMemsetAsync(cursor, 0, (NN + 66)*sizeof(int), stream);
    k_build<<<(NN*CINC + 255)/256, 256, 0, stream>>>(edges, cursor, w1, off1, w2, off2,
                                                     Wcb1, Wcb2, sei, xc, xbf);
    k_hist   <<<(NN + 255)/256, 256, 0, stream>>>(cursor, bins);
    k_prefix <<<1, 64, 0, stream>>>(bins, base);
    k_scatter<<<(NN + 255)/256, 256, 0, stream>>>(cursor, base, order);
    k_transpose<<<NN/NPB, 256, 0, stream>>>(cursor, order, sei, stenc4,
                                            stenT, srcs_s, nt_s);
    k_conv<false><<<NN/NPB, 256, 0, stream>>>(xbf, order, nt_s, srcs_s, stenT,
                                              Wcb1, b1, nullptr, nullptr, nullptr, hbf);
    k_conv<true> <<<NN/NPB, 256, 0, stream>>>(hbf, order, nt_s, srcs_s, stenT,
                                              Wcb2, b2, xc, resw, out, nullptr);
}

// Round 2
// 214.610 us; speedup vs baseline: 1.1284x; 1.1284x over previous
//
#include <hip/hip_runtime.h>

#define NN   10000
#define EE   160000
#define CINC 32
#define COUTC 32
#define RRR  6
#define MMM  3
#define RM   (RRR*MMM)      // 18
#define KK   (RM*CINC)      // 576
#define NPB  8              // nodes per block (one wave each)
#define CE   8              // edges staged per node per chunk
#define CAP  64             // fixed bucket capacity per node (mean degree 16)
#define AROW 592            // agg row stride in bf16 elems (576 + 16 pad)
#define WSZ  18432          // shorts per Wt plane: 18*2*64*8
#define EPSV 1e-8f

typedef __attribute__((ext_vector_type(8))) short bf16x8;
typedef __attribute__((ext_vector_type(4))) float f32x4;

__device__ inline short f2bf(float f) {            // round-to-nearest-even
    unsigned u = __float_as_uint(f);
    u = (u + 0x7FFF + ((u >> 16) & 1)) >> 16;
    return (short)u;
}

// ---------------- build: fragment-major bf16 weight planes + bucket scatter ----------------
// Wt layout: addr(plane, r, n2, lane, kk) = plane*WSZ + ((r*2+n2)*64 + lane)*8 + kk
// where for einsum lane l: quad=l>>4, nn16=l&15, fragment B[k=r*32+quad*8+kk][d=n2*16+nn16].
// Each einsum load instr then reads 64 lanes x 16B fully contiguous (1 KiB).

__global__ void __launch_bounds__(256)
k_build(const int* __restrict__ edges, int* __restrict__ cursor,
        const float* __restrict__ w1, const float* __restrict__ off1,
        const float* __restrict__ w2, const float* __restrict__ off2,
        short* __restrict__ Wcb1, short* __restrict__ Wcb2,
        int2* __restrict__ sei)
{
    int i = blockIdx.x*blockDim.x + threadIdx.x;
    if (i < KK*COUTC) {
        int d = i & 31;
        int k = i >> 5;                 // einsum K index = rm*32 + c
        int c = k & 31;
        int r_ = k >> 5;                // 0..17
        int q  = (k >> 3) & 3;          // quad within r
        int kk = k & 7;
        int l  = q*16 + (d & 15);
        int n2 = d >> 4;
        int addr = ((r_*2 + n2)*64 + l)*8 + kk;
        float o1 = off1[c*COUTC + d];
        float o2 = off2[c*COUTC + d];
        float s1 = sinf(o1), c1 = cosf(o1);
        float s2 = sinf(o2), c2 = cosf(o2);
        Wcb1[addr]       = f2bf(w1[i]*c1);
        Wcb1[WSZ + addr] = f2bf(w1[i]*s1);
        Wcb2[addr]       = f2bf(w2[i]*c2);
        Wcb2[WSZ + addr] = f2bf(w2[i]*s2);
    }
    if (i < EE) {
        int src = edges[2*i];
        int tgt = edges[2*i+1];
        int pos = atomicAdd(&cursor[tgt], 1);
        if (pos < CAP) sei[tgt*CAP + pos] = make_int2(src, i);
    }
}

// ---------------- degree ordering (desc), parallelized counting sort ----------------
__global__ void __launch_bounds__(256)
k_hist(const int* __restrict__ cursor, int* __restrict__ bins) {
    int n = blockIdx.x*blockDim.x + threadIdx.x;
    if (n < NN) { int d = cursor[n]; if (d > CAP) d = CAP; atomicAdd(&bins[d], 1); }
}
__global__ void k_prefix(const int* __restrict__ bins, int* __restrict__ base) {
    if (threadIdx.x == 0) {
        int run = 0;
        for (int b = CAP; b >= 0; --b) { base[b] = run; run += bins[b]; }
    }
}
__global__ void __launch_bounds__(256)
k_scatter(const int* __restrict__ cursor, int* __restrict__ base, int* __restrict__ order) {
    int n = blockIdx.x*blockDim.x + threadIdx.x;
    if (n < NN) {
        int d = cursor[n]; if (d > CAP) d = CAP;
        int r = atomicAdd(&base[d], 1);
        order[r] = n;
    }
}

// ---------------- fused conv: pipelined fp32 edge phase + bf16 MFMA einsum ----------------
// 8 nodes/block, 512 threads = 8 waves, 1 node/wave. Per-node (src,eid) in
// registers (lane l = slot l, int2). Chunk loop software-pipelined. ALL __shfl
// broadcasts execute unconditionally with the full wave; only the dependent
// global loads are predicated. Einsum via mfma_f32_16x16x32_bf16 with
// fragment-major W (coalesced 1 KiB B-loads).

template<bool FINAL>
__global__ void __launch_bounds__(512)
k_conv(const float2* __restrict__ xin,      // (NN,32) complex input
       const int*  __restrict__ cnts,       // (NN) per-node edge count
       const int*  __restrict__ order,      // (NN) degree-sorted node ids (desc)
       const int2* __restrict__ sei,        // (NN*CAP) (src,eid) buckets
       const float4* __restrict__ stenc4,   // (EE,9) float4 = (EE,18) complex
       const short* __restrict__ Wcb,       // fragment-major [re|im] planes
       const float* __restrict__ bias,      // (32)
       const float2* __restrict__ xres,     // (NN,32) original xc (FINAL)
       const float2* __restrict__ resw,     // (32,32) complex (FINAL)
       float2* __restrict__ out)            // (NN,32) complex
{
    __shared__ __align__(16) short aggS[2*NPB*AROW];     // 18944 B; later dump
    __shared__ __align__(16) float4 sten[NPB*2*CE*9];    // 18432 B dbuf stage
    __shared__ int nid[NPB];
    int t = threadIdx.x;
    int g = t >> 6;                     // wave = node slot 0..7
    int l = t & 63;

    if (t < NPB) nid[t] = order[blockIdx.x*NPB + t];
    __syncthreads();

    // ---- edge aggregation (fp32, pipelined) ----
    {
        int n = nid[g];
        int c = l & 31;
        int h = l >> 5;                 // half: alternate edges
        int cnt = cnts[n]; if (cnt > CAP) cnt = CAP;
        int beg = n*CAP;
        int srcAll = 0, eidAll = 0;
        if (l < cnt) { int2 v = sei[beg + l]; srcAll = v.x; eidAll = v.y; }

        // staging slot assignment (loop-invariant): lane covers idx l and l+64
        int e0 = l/9,      cp0 = l - 9*e0;
        int e1 = (l+64)/9, cp1 = (l+64) - 9*e1;

        float4* bufA = sten + g*(2*CE*9);
        float4* bufB = bufA + CE*9;

        float2 acc[RM];
        #pragma unroll
        for (int k = 0; k < RM; ++k) acc[k] = make_float2(0.f, 0.f);

        int nchunks = (cnt + CE - 1) / CE;
        float4 r0 = make_float4(0,0,0,0), r1 = r0;
        float2 xq[CE/2], xn[CE/2];

        auto stage_load = [&](int ck) {
            int ne = cnt - ck*CE; if (ne > CE) ne = CE;
            int nf4 = ne*9;
            int s0i = ck*CE + e0; if (s0i > 63) s0i = 63;
            int s1i = ck*CE + e1; if (s1i > 63) s1i = 63;
            int eidA = __shfl(eidAll, s0i, 64);
            int eidB = __shfl(eidAll, s1i, 64);
            r0 = make_float4(0,0,0,0); r1 = r0;
            if (l < nf4)      r0 = stenc4[(size_t)eidA*9 + cp0];
            if (l + 64 < nf4) r1 = stenc4[(size_t)eidB*9 + cp1];
        };
        auto load_x = [&](int ck, float2* xr) {
            int ne = cnt - ck*CE; if (ne > CE) ne = CE;
            #pragma unroll
            for (int i = 0; i < CE/2; ++i) {
                int le = h + 2*i;
                int sl = ck*CE + le; if (sl > 63) sl = 63;
                int s = __shfl(srcAll, sl, 64);      // unconditional
                float2 v = make_float2(0.f, 0.f);
                if (le < ne) v = xin[(size_t)s*CINC + c];
                xr[i] = v;
            }
        };
        auto stage_write = [&](float4* dst, int ck) {
            int ne = cnt - ck*CE; if (ne > CE) ne = CE;
            int nf4 = ne*9;
            if (l < nf4)      dst[l] = r0;
            if (l + 64 < nf4) dst[l+64] = r1;
        };

        if (nchunks > 0) {
            stage_load(0); load_x(0, xq); stage_write(bufA, 0);
            for (int ck = 0; ck < nchunks; ++ck) {
                float4* cur = (ck & 1) ? bufB : bufA;
                float4* nxt = (ck & 1) ? bufA : bufB;
                bool more = (ck + 1 < nchunks);
                if (more) { stage_load(ck+1); load_x(ck+1, xn); }
                int ne = cnt - ck*CE; if (ne > CE) ne = CE;
                #pragma unroll
                for (int i = 0; i < CE/2; ++i) {
                    int le = h + 2*i;
                    if (le < ne) {
                        const float4* sp = cur + le*9;
                        float2 xv = xq[i];
                        #pragma unroll
                        for (int j = 0; j < 9; ++j) {
                            float4 s = sp[j];
                            acc[2*j].x   = fmaf(s.x, xv.x, fmaf(-s.y, xv.y, acc[2*j].x));
                            acc[2*j].y   = fmaf(s.x, xv.y, fmaf( s.y, xv.x, acc[2*j].y));
                            acc[2*j+1].x = fmaf(s.z, xv.x, fmaf(-s.w, xv.y, acc[2*j+1].x));
                            acc[2*j+1].y = fmaf(s.z, xv.y, fmaf( s.w, xv.x, acc[2*j+1].y));
                        }
                    }
                }
                if (more) {
                    stage_write(nxt, ck+1);
                    #pragma unroll
                    for (int i = 0; i < CE/2; ++i) xq[i] = xn[i];
                }
            }
        }

        #pragma unroll
        for (int k = 0; k < RM; ++k) {
            acc[k].x += __shfl_down(acc[k].x, 32, 64);
            acc[k].y += __shfl_down(acc[k].y, 32, 64);
        }
        if (h == 0) {                   // bf16 agg rows (deg==0 -> zeros)
            #pragma unroll
            for (int k = 0; k < RM; ++k) {
                aggS[g*AROW + k*32 + c]            = f2bf(acc[k].x);
                aggS[NPB*AROW + g*AROW + k*32 + c] = f2bf(acc[k].y);
            }
        }
    }
    __syncthreads();

    // ---- einsum via MFMA: D[m][d] = sum_k agg[m][k] * Wc[k][d] ----
    int quad = l >> 4;
    int nn16 = l & 15;
    int mrow = (nn16 < NPB) ? nn16 : NPB-1;       // rows >=8 ignored (dup of 7)
    int rm0 = (g < 2) ? 3*g : 2*g + 2;            // waves 0-1: 3 rm, else 2 rm
    int nrm = (g < 2) ? 3 : 2;
    const short* aggR = aggS;
    const short* aggI = aggS + NPB*AROW;
    const short* Wr = Wcb;
    const short* Wi = Wcb + WSZ;
    int lbase = l*8;

    f32x4 Prr[2], Pii[2], Pri[2], Pir[2];
    #pragma unroll
    for (int nt = 0; nt < 2; ++nt) {
        Prr[nt] = (f32x4)(0.f); Pii[nt] = (f32x4)(0.f);
        Pri[nt] = (f32x4)(0.f); Pir[nt] = (f32x4)(0.f);
    }
    for (int r = rm0; r < rm0 + nrm; ++r) {
        int koff = r*32 + quad*8;
        bf16x8 ar = *(const bf16x8*)(aggR + mrow*AROW + koff);
        bf16x8 ai = *(const bf16x8*)(aggI + mrow*AROW + koff);
        #pragma unroll
        for (int nt = 0; nt < 2; ++nt) {
            int woff = ((r*2 + nt) << 9) + lbase;     // fragment-major, coalesced
            bf16x8 br = *(const bf16x8*)(Wr + woff);
            bf16x8 bi = *(const bf16x8*)(Wi + woff);
            Prr[nt] = __builtin_amdgcn_mfma_f32_16x16x32_bf16(ar, br, Prr[nt], 0, 0, 0);
            Pii[nt] = __builtin_amdgcn_mfma_f32_16x16x32_bf16(ai, bi, Pii[nt], 0, 0, 0);
            Pri[nt] = __builtin_amdgcn_mfma_f32_16x16x32_bf16(ar, bi, Pri[nt], 0, 0, 0);
            Pir[nt] = __builtin_amdgcn_mfma_f32_16x16x32_bf16(ai, br, Pir[nt], 0, 0, 0);
        }
    }
    __syncthreads();                    // all agg reads done; reuse as dump

    // ---- dump partials: [wave][m][d] float2, rows m<8 only (quads 0,1) ----
    float2* dump = (float2*)aggS;       // 16384 B <= 18944
    if (quad < 2) {
        #pragma unroll
        for (int reg = 0; reg < 4; ++reg) {
            int m = quad*4 + reg;
            #pragma unroll
            for (int nt = 0; nt < 2; ++nt) {
                int d = nt*16 + nn16;
                dump[((size_t)g*NPB + m)*COUTC + d] =
                    make_float2(Prr[nt][reg] - Pii[nt][reg],
                                Pri[nt][reg] + Pir[nt][reg]);
            }
        }
    }
    __syncthreads();

    // ---- reduce 8 waves, residual, nonlinearity ----
    if (t < NPB*COUTC) {
        int m = t >> 5, d = t & 31;
        int n = nid[m];
        float2 hv = make_float2(0.f, 0.f);
        #pragma unroll
        for (int w = 0; w < NPB; ++w) {
            float2 v = dump[((size_t)w*NPB + m)*COUTC + d];
            hv.x += v.x; hv.y += v.y;
        }
        if (FINAL) {
            const float2* xr = xres + (size_t)n * CINC;
            #pragma unroll
            for (int c = 0; c < CINC; ++c) {
                float2 xv = xr[c];
                float2 w = resw[c*COUTC + d];
                hv.x += xv.x*w.x - xv.y*w.y;
                hv.y += xv.x*w.y + xv.y*w.x;
            }
        }
        float mag = sqrtf(hv.x*hv.x + hv.y*hv.y);
        float num = mag + bias[d]; if (num < 0.f) num = 0.f;
        float den = (mag > EPSV) ? mag : EPSV;
        float f = num / den;
        out[(size_t)n*COUTC + d] = make_float2(f*hv.x, f*hv.y);
    }
}

// ---------------- launch ----------------

extern "C" void kernel_launch(void* const* d_in, const int* in_sizes, int n_in,
                              void* d_out, int out_size, void* d_ws, size_t ws_size,
                              hipStream_t stream) {
    const float2* xc   = (const float2*)d_in[0];   // (N,32,2) -> complex
    const int*   edges = (const int*)  d_in[1];    // (E,2)
    const float4* stenc4 = (const float4*)d_in[2]; // (E,6,3,2) -> (E,9) float4
    const float* w1    = (const float*)d_in[3];
    const float* off1  = (const float*)d_in[4];
    const float* b1    = (const float*)d_in[5];
    const float* w2    = (const float*)d_in[6];
    const float* off2  = (const float*)d_in[7];
    const float* b2    = (const float*)d_in[8];
    const float2* resw = (const float2*)d_in[9];   // (32,32) complex
    float2* out = (float2*)d_out;

    char* ws = (char*)d_ws;
    size_t o = 0;
    auto alloc = [&](size_t bytes) {
        o = (o + 255) & ~(size_t)255;
        size_t r = o; o += bytes; return r;
    };
    int*    cursor = (int*)  (ws + alloc((NN + 66)*sizeof(int)));  // +bins tail
    int*    bins   = cursor + NN;
    int*    base   = (int*)  (ws + alloc(66*sizeof(int)));
    int*    order  = (int*)  (ws + alloc(NN*sizeof(int)));
    int2*   sei    = (int2*) (ws + alloc((size_t)NN*CAP*sizeof(int2)));
    short*  Wcb1   = (short*)(ws + alloc((size_t)2*WSZ*sizeof(short)));
    short*  Wcb2   = (short*)(ws + alloc((size_t)2*WSZ*sizeof(short)));
    float2* h      = (float2*)(ws + alloc((size_t)NN*COUTC*sizeof(float2)));
    (void)ws_size; (void)in_sizes; (void)n_in; (void)out_size;

    hipMemsetAsync(cursor, 0, (NN + 66)*sizeof(int), stream);
    k_build<<<(EE+255)/256, 256, 0, stream>>>(edges, cursor, w1, off1, w2, off2,
                                              Wcb1, Wcb2, sei);
    k_hist   <<<(NN + 255)/256, 256, 0, stream>>>(cursor, bins);
    k_prefix <<<1, 64, 0, stream>>>(bins, base);
    k_scatter<<<(NN + 255)/256, 256, 0, stream>>>(cursor, base, order);

    k_conv<false><<<NN/NPB, 512, 0, stream>>>(xc, cursor, order, sei, stenc4,
                                              Wcb1, b1, nullptr, nullptr, h);
    k_conv<true> <<<NN/NPB, 512, 0, stream>>>(h, cursor, order, sei, stenc4,
                                              Wcb2, b2, xc, resw, out);
}

// Round 3
// 176.424 us; speedup vs baseline: 1.3727x; 1.2164x over previous
//
#include <hip/hip_runtime.h>

#define NN   10000
#define EE   160000
#define CINC 32
#define COUTC 32
#define RRR  6
#define MMM  3
#define RM   (RRR*MMM)      // 18
#define KK   (RM*CINC)      // 576
#define NPB  4              // nodes per block (one wave each), 256 threads
#define CE   8              // edges staged per node per chunk
#define CAP  64             // fixed bucket capacity per node (mean degree 16)
#define AROW 592            // agg row stride in bf16 elems (576 + 16 pad)
#define WSZ  18432          // shorts per Wt plane: 18*2*64*8
#define EPSV 1e-8f

typedef __attribute__((ext_vector_type(8))) short bf16x8;
typedef __attribute__((ext_vector_type(4))) float f32x4;

__device__ inline short f2bf(float f) {            // round-to-nearest-even
    unsigned u = __float_as_uint(f);
    u = (u + 0x7FFF + ((u >> 16) & 1)) >> 16;
    return (short)u;
}

// ---------------- build: fragment-major bf16 weight planes + bucket scatter ----------------
// Wt layout: addr(plane, r, n2, lane, kk) = plane*WSZ + ((r*2+n2)*64 + lane)*8 + kk
// where for einsum lane l: quad=l>>4, nn16=l&15, fragment B[k=r*32+quad*8+kk][d=n2*16+nn16].
// Each einsum load instr then reads 64 lanes x 16B fully contiguous (1 KiB).

__global__ void __launch_bounds__(256)
k_build(const int* __restrict__ edges, int* __restrict__ cursor,
        const float* __restrict__ w1, const float* __restrict__ off1,
        const float* __restrict__ w2, const float* __restrict__ off2,
        short* __restrict__ Wcb1, short* __restrict__ Wcb2,
        int2* __restrict__ sei)
{
    int i = blockIdx.x*blockDim.x + threadIdx.x;
    if (i < KK*COUTC) {
        int d = i & 31;
        int k = i >> 5;                 // einsum K index = rm*32 + c
        int c = k & 31;
        int r_ = k >> 5;                // 0..17
        int q  = (k >> 3) & 3;          // quad within r
        int kk = k & 7;
        int l  = q*16 + (d & 15);
        int n2 = d >> 4;
        int addr = ((r_*2 + n2)*64 + l)*8 + kk;
        float o1 = off1[c*COUTC + d];
        float o2 = off2[c*COUTC + d];
        float s1 = sinf(o1), c1 = cosf(o1);
        float s2 = sinf(o2), c2 = cosf(o2);
        Wcb1[addr]       = f2bf(w1[i]*c1);
        Wcb1[WSZ + addr] = f2bf(w1[i]*s1);
        Wcb2[addr]       = f2bf(w2[i]*c2);
        Wcb2[WSZ + addr] = f2bf(w2[i]*s2);
    }
    if (i < EE) {
        int src = edges[2*i];
        int tgt = edges[2*i+1];
        int pos = atomicAdd(&cursor[tgt], 1);
        if (pos < CAP) sei[tgt*CAP + pos] = make_int2(src, i);
    }
}

// ---------------- degree counting-sort, DESCENDING (single block, 1 launch) ----------------
// Hist via LDS atomics; suffix-sum base via 128-thread Hillis-Steele scan
// (replaces the serial 65-iteration thread-0 loop); scatter via LDS atomics.

__global__ void __launch_bounds__(1024)
k_order(const int* __restrict__ cnts, int* __restrict__ order) {
    __shared__ int bins[CAP+1];
    __shared__ int suf[128];
    __shared__ int base[CAP+1];
    int t = threadIdx.x;
    if (t <= CAP) bins[t] = 0;
    __syncthreads();
    for (int n = t; n < NN; n += 1024) {
        int d = cnts[n]; if (d > CAP) d = CAP;
        atomicAdd(&bins[d], 1);
    }
    __syncthreads();
    if (t < 128) suf[t] = (t <= CAP) ? bins[t] : 0;
    __syncthreads();
    #pragma unroll
    for (int s = 1; s < 128; s <<= 1) {
        int v = 0;
        if (t < 128 && t + s < 128) v = suf[t+s];
        __syncthreads();
        if (t < 128) suf[t] += v;
        __syncthreads();
    }
    if (t <= CAP) base[t] = (t+1 < 128) ? suf[t+1] : 0;   // #nodes with deg > t
    __syncthreads();
    for (int n = t; n < NN; n += 1024) {
        int d = cnts[n]; if (d > CAP) d = CAP;
        int r = atomicAdd(&base[d], 1);
        order[r] = n;
    }
}

// ---------------- fused conv: pipelined fp32 edge phase + bf16 MFMA einsum ----------------
// 4 nodes/block, 256 threads = 4 waves, 1 node/wave (was 8: halving the block
// doubles resident blocks/CU to 8, decouples syncthreads across fewer waves,
// and doubles the pool of independent blocks hiding stage-load latency).
// Einsum via mfma_f32_16x16x32_bf16 with fragment-major W (coalesced 1 KiB
// B-loads).

template<bool FINAL>
__global__ void __launch_bounds__(256)
k_conv(const float2* __restrict__ xin,      // (NN,32) complex input
       const int*  __restrict__ cnts,       // (NN) per-node edge count
       const int*  __restrict__ order,      // (NN) degree-sorted node ids (desc)
       const int2* __restrict__ sei,        // (NN*CAP) (src,eid) buckets
       const float4* __restrict__ stenc4,   // (EE,9) float4 = (EE,18) complex
       const short* __restrict__ Wcb,       // fragment-major [re|im] planes
       const float* __restrict__ bias,      // (32)
       const float2* __restrict__ xres,     // (NN,32) original xc (FINAL)
       const float2* __restrict__ resw,     // (32,32) complex (FINAL)
       float2* __restrict__ out)            // (NN,32) complex
{
    __shared__ __align__(16) short aggS[2*NPB*AROW];     // 9472 B; later dump
    __shared__ __align__(16) float4 sten[NPB*2*CE*9];    // 9216 B dbuf stage
    __shared__ int nid[NPB];
    int t = threadIdx.x;
    int g = t >> 6;                     // wave = node slot 0..3
    int l = t & 63;

    if (t < NPB) nid[t] = order[blockIdx.x*NPB + t];
    __syncthreads();

    // ---- edge aggregation (fp32, pipelined) ----
    {
        int n = nid[g];
        int c = l & 31;
        int h = l >> 5;                 // half: alternate edges
        int cnt = cnts[n]; if (cnt > CAP) cnt = CAP;
        int beg = n*CAP;
        int srcAll = 0, eidAll = 0;
        if (l < cnt) { int2 v = sei[beg + l]; srcAll = v.x; eidAll = v.y; }

        // staging slot assignment (loop-invariant): lane covers idx l and l+64
        int e0 = l/9,      cp0 = l - 9*e0;
        int e1 = (l+64)/9, cp1 = (l+64) - 9*e1;

        float4* bufA = sten + g*(2*CE*9);
        float4* bufB = bufA + CE*9;

        float2 acc[RM];
        #pragma unroll
        for (int k = 0; k < RM; ++k) acc[k] = make_float2(0.f, 0.f);

        int nchunks = (cnt + CE - 1) / CE;
        float4 r0 = make_float4(0,0,0,0), r1 = r0;
        float2 xq[CE/2], xn[CE/2];

        auto stage_load = [&](int ck) {
            int ne = cnt - ck*CE; if (ne > CE) ne = CE;
            int nf4 = ne*9;
            int s0i = ck*CE + e0; if (s0i > 63) s0i = 63;
            int s1i = ck*CE + e1; if (s1i > 63) s1i = 63;
            int eidA = __shfl(eidAll, s0i, 64);
            int eidB = __shfl(eidAll, s1i, 64);
            r0 = make_float4(0,0,0,0); r1 = r0;
            if (l < nf4)      r0 = stenc4[(size_t)eidA*9 + cp0];
            if (l + 64 < nf4) r1 = stenc4[(size_t)eidB*9 + cp1];
        };
        auto load_x = [&](int ck, float2* xr) {
            int ne = cnt - ck*CE; if (ne > CE) ne = CE;
            #pragma unroll
            for (int i = 0; i < CE/2; ++i) {
                int le = h + 2*i;
                int sl = ck*CE + le; if (sl > 63) sl = 63;
                int s = __shfl(srcAll, sl, 64);      // unconditional
                float2 v = make_float2(0.f, 0.f);
                if (le < ne) v = xin[(size_t)s*CINC + c];
                xr[i] = v;
            }
        };
        auto stage_write = [&](float4* dst, int ck) {
            int ne = cnt - ck*CE; if (ne > CE) ne = CE;
            int nf4 = ne*9;
            if (l < nf4)      dst[l] = r0;
            if (l + 64 < nf4) dst[l+64] = r1;
        };

        if (nchunks > 0) {
            stage_load(0); load_x(0, xq); stage_write(bufA, 0);
            for (int ck = 0; ck < nchunks; ++ck) {
                float4* cur = (ck & 1) ? bufB : bufA;
                float4* nxt = (ck & 1) ? bufA : bufB;
                bool more = (ck + 1 < nchunks);
                if (more) { stage_load(ck+1); load_x(ck+1, xn); }
                int ne = cnt - ck*CE; if (ne > CE) ne = CE;
                #pragma unroll
                for (int i = 0; i < CE/2; ++i) {
                    int le = h + 2*i;
                    if (le < ne) {
                        const float4* sp = cur + le*9;
                        float2 xv = xq[i];
                        #pragma unroll
                        for (int j = 0; j < 9; ++j) {
                            float4 s = sp[j];
                            acc[2*j].x   = fmaf(s.x, xv.x, fmaf(-s.y, xv.y, acc[2*j].x));
                            acc[2*j].y   = fmaf(s.x, xv.y, fmaf( s.y, xv.x, acc[2*j].y));
                            acc[2*j+1].x = fmaf(s.z, xv.x, fmaf(-s.w, xv.y, acc[2*j+1].x));
                            acc[2*j+1].y = fmaf(s.z, xv.y, fmaf( s.w, xv.x, acc[2*j+1].y));
                        }
                    }
                }
                if (more) {
                    stage_write(nxt, ck+1);
                    #pragma unroll
                    for (int i = 0; i < CE/2; ++i) xq[i] = xn[i];
                }
            }
        }

        #pragma unroll
        for (int k = 0; k < RM; ++k) {
            acc[k].x += __shfl_down(acc[k].x, 32, 64);
            acc[k].y += __shfl_down(acc[k].y, 32, 64);
        }
        if (h == 0) {                   // bf16 agg rows (deg==0 -> zeros)
            #pragma unroll
            for (int k = 0; k < RM; ++k) {
                aggS[g*AROW + k*32 + c]            = f2bf(acc[k].x);
                aggS[NPB*AROW + g*AROW + k*32 + c] = f2bf(acc[k].y);
            }
        }
    }
    __syncthreads();

    // ---- einsum via MFMA: D[m][d] = sum_k agg[m][k] * Wc[k][d] ----
    int quad = l >> 4;
    int nn16 = l & 15;
    int mrow = (nn16 < NPB) ? nn16 : NPB-1;       // rows >=4 ignored (dup of 3)
    int rm0 = (g < 2) ? 5*g : 10 + 4*(g-2);       // waves: 5,5,4,4 rm rows
    int nrm = (g < 2) ? 5 : 4;
    const short* aggR = aggS;
    const short* aggI = aggS + NPB*AROW;
    const short* Wr = Wcb;
    const short* Wi = Wcb + WSZ;
    int lbase = l*8;

    f32x4 Prr[2], Pii[2], Pri[2], Pir[2];
    #pragma unroll
    for (int nt = 0; nt < 2; ++nt) {
        Prr[nt] = (f32x4)(0.f); Pii[nt] = (f32x4)(0.f);
        Pri[nt] = (f32x4)(0.f); Pir[nt] = (f32x4)(0.f);
    }
    for (int r = rm0; r < rm0 + nrm; ++r) {
        int koff = r*32 + quad*8;
        bf16x8 ar = *(const bf16x8*)(aggR + mrow*AROW + koff);
        bf16x8 ai = *(const bf16x8*)(aggI + mrow*AROW + koff);
        #pragma unroll
        for (int nt = 0; nt < 2; ++nt) {
            int woff = ((r*2 + nt) << 9) + lbase;     // fragment-major, coalesced
            bf16x8 br = *(const bf16x8*)(Wr + woff);
            bf16x8 bi = *(const bf16x8*)(Wi + woff);
            Prr[nt] = __builtin_amdgcn_mfma_f32_16x16x32_bf16(ar, br, Prr[nt], 0, 0, 0);
            Pii[nt] = __builtin_amdgcn_mfma_f32_16x16x32_bf16(ai, bi, Pii[nt], 0, 0, 0);
            Pri[nt] = __builtin_amdgcn_mfma_f32_16x16x32_bf16(ar, bi, Pri[nt], 0, 0, 0);
            Pir[nt] = __builtin_amdgcn_mfma_f32_16x16x32_bf16(ai, br, Pir[nt], 0, 0, 0);
        }
    }
    __syncthreads();                    // all agg reads done; reuse as dump

    // ---- dump partials: [wave][m][d] float2, rows m<4 only (quad 0) ----
    float2* dump = (float2*)aggS;       // 4096 B <= 9472
    if (quad == 0) {
        #pragma unroll
        for (int reg = 0; reg < 4; ++reg) {
            int m = reg;
            #pragma unroll
            for (int nt = 0; nt < 2; ++nt) {
                int d = nt*16 + nn16;
                dump[((size_t)g*NPB + m)*COUTC + d] =
                    make_float2(Prr[nt][reg] - Pii[nt][reg],
                                Pri[nt][reg] + Pir[nt][reg]);
            }
        }
    }
    __syncthreads();

    // ---- reduce 4 waves, residual, nonlinearity ----
    if (t < NPB*COUTC) {
        int m = t >> 5, d = t & 31;
        int n = nid[m];
        float2 hv = make_float2(0.f, 0.f);
        #pragma unroll
        for (int w = 0; w < NPB; ++w) {
            float2 v = dump[((size_t)w*NPB + m)*COUTC + d];
            hv.x += v.x; hv.y += v.y;
        }
        if (FINAL) {
            const float2* xr = xres + (size_t)n * CINC;
            #pragma unroll
            for (int c = 0; c < CINC; ++c) {
                float2 xv = xr[c];
                float2 w = resw[c*COUTC + d];
                hv.x += xv.x*w.x - xv.y*w.y;
                hv.y += xv.x*w.y + xv.y*w.x;
            }
        }
        float mag = sqrtf(hv.x*hv.x + hv.y*hv.y);
        float num = mag + bias[d]; if (num < 0.f) num = 0.f;
        float den = (mag > EPSV) ? mag : EPSV;
        float f = num / den;
        out[(size_t)n*COUTC + d] = make_float2(f*hv.x, f*hv.y);
    }
}

// ---------------- launch ----------------

extern "C" void kernel_launch(void* const* d_in, const int* in_sizes, int n_in,
                              void* d_out, int out_size, void* d_ws, size_t ws_size,
                              hipStream_t stream) {
    const float2* xc   = (const float2*)d_in[0];   // (N,32,2) -> complex
    const int*   edges = (const int*)  d_in[1];    // (E,2)
    const float4* stenc4 = (const float4*)d_in[2]; // (E,6,3,2) -> (E,9) float4
    const float* w1    = (const float*)d_in[3];
    const float* off1  = (const float*)d_in[4];
    const float* b1    = (const float*)d_in[5];
    const float* w2    = (const float*)d_in[6];
    const float* off2  = (const float*)d_in[7];
    const float* b2    = (const float*)d_in[8];
    const float2* resw = (const float2*)d_in[9];   // (32,32) complex
    float2* out = (float2*)d_out;

    char* ws = (char*)d_ws;
    size_t o = 0;
    auto alloc = [&](size_t bytes) {
        o = (o + 255) & ~(size_t)255;
        size_t r = o; o += bytes; return r;
    };
    int*    cursor = (int*)  (ws + alloc(NN*sizeof(int)));
    int*    order  = (int*)  (ws + alloc(NN*sizeof(int)));
    int2*   sei    = (int2*) (ws + alloc((size_t)NN*CAP*sizeof(int2)));
    short*  Wcb1   = (short*)(ws + alloc((size_t)2*WSZ*sizeof(short)));
    short*  Wcb2   = (short*)(ws + alloc((size_t)2*WSZ*sizeof(short)));
    float2* h      = (float2*)(ws + alloc((size_t)NN*COUTC*sizeof(float2)));
    (void)ws_size; (void)in_sizes; (void)n_in; (void)out_size;

    hipMemsetAsync(cursor, 0, NN*sizeof(int), stream);
    k_build<<<(EE+255)/256, 256, 0, stream>>>(edges, cursor, w1, off1, w2, off2,
                                              Wcb1, Wcb2, sei);
    k_order<<<1, 1024, 0, stream>>>(cursor, order);

    k_conv<false><<<NN/NPB, 256, 0, stream>>>(xc, cursor, order, sei, stenc4,
                                              Wcb1, b1, nullptr, nullptr, h);
    k_conv<true> <<<NN/NPB, 256, 0, stream>>>(h, cursor, order, sei, stenc4,
                                              Wcb2, b2, xc, resw, out);
}